// Round 1
// baseline (157.354 us; speedup 1.0000x reference)
//
#include <hip/hip_runtime.h>
#include <math.h>

// Problem constants (from setup_inputs)
#define B 64
#define CIN 32
#define COUT 32
#define HH 64
#define WW 64
#define E 16
#define TOPK 4

// ---------------------------------------------------------------------------
// Kernel 1: gate_x[b][c] = mean over H*W of x[b][c][:][:]
// ---------------------------------------------------------------------------
__global__ void gatex_kernel(const float* __restrict__ x, float* __restrict__ gx) {
    int bc = blockIdx.x;                 // 0..2047  (b*32 + c)
    int t  = threadIdx.x;                // 256 threads
    const float4* p = reinterpret_cast<const float4*>(x + (size_t)bc * 4096);
    float s = 0.f;
    for (int i = t; i < 1024; i += 256) {
        float4 v = p[i];
        s += (v.x + v.y) + (v.z + v.w);
    }
    // 64-lane wave reduce
    for (int off = 32; off > 0; off >>= 1) s += __shfl_down(s, off, 64);
    __shared__ float red[4];
    if ((t & 63) == 0) red[t >> 6] = s;
    __syncthreads();
    if (t == 0) gx[bc] = (red[0] + red[1] + red[2] + red[3]) * (1.f / 4096.f);
}

// ---------------------------------------------------------------------------
// Kernel 2: gating math, top-k, gates, loss.  Single block of 64 threads,
// thread b owns sample b.
// ---------------------------------------------------------------------------
__global__ void gating_kernel(const float* __restrict__ gate_x,
                              const float* __restrict__ noise,
                              const float* __restrict__ w_gate,
                              const float* __restrict__ w_noise,
                              float* __restrict__ gates_out,
                              float* __restrict__ loss_out) {
    __shared__ float s_wg[CIN * E];
    __shared__ float s_wn[CIN * E];
    __shared__ float s_g[B][E];
    __shared__ float s_p[B][E];
    __shared__ float s_imp[E];
    __shared__ float s_load[E];

    int t = threadIdx.x;  // 64 threads
    for (int i = t; i < CIN * E; i += 64) {
        s_wg[i] = w_gate[i];
        s_wn[i] = w_noise[i];
    }
    __syncthreads();

    int b = t;
    float gx[CIN];
    #pragma unroll
    for (int c = 0; c < CIN; c++) gx[c] = gate_x[b * CIN + c];

    float clean[E], stdv[E], noisy[E];
    #pragma unroll
    for (int e = 0; e < E; e++) {
        float s1 = 0.f, s2 = 0.f;
        #pragma unroll
        for (int c = 0; c < CIN; c++) {
            s1 += gx[c] * s_wg[c * E + e];
            s2 += gx[c] * s_wn[c * E + e];
        }
        clean[e] = s1;
        // softplus(s2) = max(s2,0) + log1p(exp(-|s2|))
        float sp = fmaxf(s2, 0.f) + log1pf(expf(-fabsf(s2)));
        stdv[e]  = sp + 0.01f;
        noisy[e] = s1 + noise[b * E + e] * stdv[e];
    }

    // softmax over E
    float m = noisy[0];
    #pragma unroll
    for (int e = 1; e < E; e++) m = fmaxf(m, noisy[e]);
    float den = 0.f;
    float lg[E];
    #pragma unroll
    for (int e = 0; e < E; e++) { lg[e] = expf(noisy[e] - m); den += lg[e]; }
    float inv = 1.f / den;
    #pragma unroll
    for (int e = 0; e < E; e++) lg[e] *= inv;

    // top-(k+1) selection (descending, stable: strict > keeps lowest index)
    float tv[TOPK + 1];
    int   ti[TOPK + 1];
    bool  used[E];
    #pragma unroll
    for (int e = 0; e < E; e++) used[e] = false;
    for (int r = 0; r < TOPK + 1; r++) {
        float best = -1.f; int bi = 0;
        for (int e = 0; e < E; e++) {
            if (!used[e] && lg[e] > best) { best = lg[e]; bi = e; }
        }
        tv[r] = best; ti[r] = bi; used[bi] = true;
    }
    float s4 = tv[0] + tv[1] + tv[2] + tv[3] + 1e-6f;
    float grow[E];
    #pragma unroll
    for (int e = 0; e < E; e++) grow[e] = 0.f;
    for (int r = 0; r < TOPK; r++) grow[ti[r]] = tv[r] / s4;

    float thr_in  = tv[TOPK];      // (k+1)-th value
    float thr_out = tv[TOPK - 1];  // k-th value

    const float INV_SQRT2 = 0.70710678118654752f;
    #pragma unroll
    for (int e = 0; e < E; e++) {
        float thr = (noisy[e] > thr_in) ? thr_in : thr_out;
        float z = (clean[e] - thr) / stdv[e];
        s_p[b][e] = 0.5f * (1.f + erff(z * INV_SQRT2));
        s_g[b][e] = grow[e];
        gates_out[b * E + e] = grow[e];
    }
    __syncthreads();

    if (t < E) {
        float si = 0.f, sl = 0.f;
        for (int bb = 0; bb < B; bb++) { si += s_g[bb][t]; sl += s_p[bb][t]; }
        s_imp[t] = si; s_load[t] = sl;
    }
    __syncthreads();

    if (t == 0) {
        float loss = 0.f;
        for (int pass = 0; pass < 2; pass++) {
            const float* v = pass == 0 ? s_imp : s_load;
            float mean = 0.f;
            for (int e = 0; e < E; e++) mean += v[e];
            mean *= (1.f / E);
            float var = 0.f;
            for (int e = 0; e < E; e++) { float d = v[e] - mean; var += d * d; }
            var *= (1.f / (E - 1));
            loss += var / (mean * mean + 1e-10f);
        }
        loss_out[0] = loss * 0.01f;
    }
}

// ---------------------------------------------------------------------------
// Kernel 3: combined per-sample weights
//   cw[b][cin][kh][kw][cout] = sum_e gates[b][e] * expert_w[e][cout][cin][kh][kw]
//   cbias[b][cout]           = sum_e gates[b][e] * expert_b[e][cout]
// ---------------------------------------------------------------------------
__global__ void combine_kernel(const float* __restrict__ gates,
                               const float* __restrict__ expert_w,
                               const float* __restrict__ expert_b,
                               float* __restrict__ cw,
                               float* __restrict__ cbias) {
    int b = blockIdx.x;
    int t = threadIdx.x;  // 256
    __shared__ float g[E];
    if (t < E) g[t] = gates[b * E + t];
    __syncthreads();

    for (int i = t; i < CIN * 9 * COUT; i += 256) {
        int cout = i & 31;
        int ck   = i >> 5;          // cin*9 + k
        int cin  = ck / 9;
        int k    = ck - cin * 9;
        float s = 0.f;
        for (int e = 0; e < E; e++) {
            float ge = g[e];
            if (ge != 0.f)
                s += ge * expert_w[(((e * COUT + cout) * CIN + cin) * 9) + k];
        }
        cw[(size_t)b * (CIN * 9 * COUT) + i] = s;
    }
    if (t < COUT) {
        float s = 0.f;
        for (int e = 0; e < E; e++) {
            float ge = g[e];
            if (ge != 0.f) s += ge * expert_b[e * COUT + t];
        }
        cbias[b * COUT + t] = s;
    }
}

// ---------------------------------------------------------------------------
// Kernel 4: direct 3x3 conv with per-sample combined weights.
//   grid = B * 16 (4-row tiles), block = 256.
//   Thread: wi = t&15 -> 4 contiguous pixels; wg = t>>4 -> (row r, cout-block cb)
//   Accumulates 8 couts x 4 pixels in registers.
// ---------------------------------------------------------------------------
#define XSTR 68
#define CCHUNK 8

__global__ void __launch_bounds__(256)
conv_kernel(const float* __restrict__ x,
            const float* __restrict__ cw,
            const float* __restrict__ cbias,
            float* __restrict__ y) {
    __shared__ __align__(16) float s_w[CIN * 9 * COUT];       // 9216 f = 36 KB
    __shared__ __align__(16) float s_x[CCHUNK * 6 * XSTR];    // 3264 f = 12.75 KB

    int bidx = blockIdx.x;
    int b  = bidx >> 4;
    int h0 = (bidx & 15) << 2;
    int t  = threadIdx.x;
    int wi = t & 15;  int w0 = wi << 2;
    int wg = t >> 4;  int r  = wg & 3;  int cb = wg >> 2;  // cout base = cb*8

    // stage combined weights for this sample
    const float* wsrc = cw + (size_t)b * (CIN * 9 * COUT);
    for (int i = t; i < CIN * 9 * COUT; i += 256) s_w[i] = wsrc[i];

    float acc[8][4];
    #pragma unroll
    for (int co = 0; co < 8; co++)
        #pragma unroll
        for (int j = 0; j < 4; j++) acc[co][j] = 0.f;

    for (int cc = 0; cc < CIN / CCHUNK; cc++) {
        int ci0 = cc * CCHUNK;
        __syncthreads();   // also covers initial weight staging (cc==0)
        // stage x chunk: rows h0-1 .. h0+4, cols -1 .. 64  (66 cols)
        for (int i = t; i < CCHUNK * 6 * 66; i += 256) {
            int c   = i / (6 * 66);
            int rem = i - c * (6 * 66);
            int rr  = rem / 66;
            int col = rem - rr * 66;
            int gr = h0 - 1 + rr;
            int gc = col - 1;
            float v = 0.f;
            if ((unsigned)gr < 64u && (unsigned)gc < 64u)
                v = x[(size_t)(((b * CIN + ci0 + c) * 64 + gr) << 6) + gc];
            s_x[(c * 6 + rr) * XSTR + col] = v;
        }
        __syncthreads();

        #pragma unroll 2
        for (int c = 0; c < CCHUNK; c++) {
            #pragma unroll
            for (int kh = 0; kh < 3; kh++) {
                const float* xrow = &s_x[(c * 6 + r + kh) * XSTR + w0];
                float4 v0 = *reinterpret_cast<const float4*>(xrow);
                float win[6] = { v0.x, v0.y, v0.z, v0.w, xrow[4], xrow[5] };
                const float* wrow = &s_w[((ci0 + c) * 9 + kh * 3) * 32 + cb * 8];
                #pragma unroll
                for (int kw = 0; kw < 3; kw++) {
                    float4 wa = *reinterpret_cast<const float4*>(wrow + kw * 32);
                    float4 wb = *reinterpret_cast<const float4*>(wrow + kw * 32 + 4);
                    float wv[8] = { wa.x, wa.y, wa.z, wa.w, wb.x, wb.y, wb.z, wb.w };
                    #pragma unroll
                    for (int co = 0; co < 8; co++)
                        #pragma unroll
                        for (int j = 0; j < 4; j++)
                            acc[co][j] += wv[co] * win[kw + j];
                }
            }
        }
    }

    // epilogue: add combined bias, store
    int hrow = h0 + r;
    #pragma unroll
    for (int co = 0; co < 8; co++) {
        float bias = cbias[b * COUT + cb * 8 + co];
        float4 o;
        o.x = acc[co][0] + bias;
        o.y = acc[co][1] + bias;
        o.z = acc[co][2] + bias;
        o.w = acc[co][3] + bias;
        *reinterpret_cast<float4*>(
            &y[(size_t)(((b * COUT + cb * 8 + co) * 64 + hrow) << 6) + w0]) = o;
    }
}

// ---------------------------------------------------------------------------
extern "C" void kernel_launch(void* const* d_in, const int* in_sizes, int n_in,
                              void* d_out, int out_size, void* d_ws, size_t ws_size,
                              hipStream_t stream) {
    const float* x        = (const float*)d_in[0];
    const float* noise    = (const float*)d_in[1];
    const float* w_gate   = (const float*)d_in[2];
    const float* w_noise  = (const float*)d_in[3];
    const float* expert_w = (const float*)d_in[4];
    const float* expert_b = (const float*)d_in[5];

    float* y    = (float*)d_out;                  // B*COUT*H*W = 8388608
    float* loss = y + (size_t)B * COUT * HH * WW; // last element

    float* ws     = (float*)d_ws;
    float* gate_x = ws;            // 2048
    float* gates  = ws + 2048;     // 1024
    float* cbias  = ws + 3072;     // 2048
    float* cw     = ws + 5120;     // 589824

    gatex_kernel<<<B * CIN, 256, 0, stream>>>(x, gate_x);
    gating_kernel<<<1, 64, 0, stream>>>(gate_x, noise, w_gate, w_noise, gates, loss);
    combine_kernel<<<B, 256, 0, stream>>>(gates, expert_w, expert_b, cw, cbias);
    conv_kernel<<<B * 16, 256, 0, stream>>>(x, cw, cbias, y);
}

// Round 2
// 71.148 us; speedup vs baseline: 2.2116x; 2.2116x over previous
//
#include <hip/hip_runtime.h>
#include <math.h>

// Problem constants
#define B 64
#define CIN 32
#define COUT 32
#define HH 64
#define WW 64
#define E 16
#define TOPK 4

typedef __attribute__((ext_vector_type(8))) short short8;
typedef __attribute__((ext_vector_type(4))) float f32x4;

// round-to-nearest-even f32 -> bf16 bits
__device__ __forceinline__ unsigned short f2bf(float f) {
    unsigned int u = __float_as_uint(f);
    u += 0x7fffu + ((u >> 16) & 1u);
    return (unsigned short)(u >> 16);
}

// ---------------------------------------------------------------------------
// Kernel 1: gate_x[b][c] = mean over H*W of x[b][c][:][:]
// ---------------------------------------------------------------------------
__global__ void gatex_kernel(const float* __restrict__ x, float* __restrict__ gx) {
    int bc = blockIdx.x;                 // b*32 + c
    int t  = threadIdx.x;                // 256
    const float4* p = reinterpret_cast<const float4*>(x + (size_t)bc * 4096);
    float s = 0.f;
    for (int i = t; i < 1024; i += 256) {
        float4 v = p[i];
        s += (v.x + v.y) + (v.z + v.w);
    }
    for (int off = 32; off > 0; off >>= 1) s += __shfl_down(s, off, 64);
    __shared__ float red[4];
    if ((t & 63) == 0) red[t >> 6] = s;
    __syncthreads();
    if (t == 0) gx[bc] = (red[0] + red[1] + red[2] + red[3]) * (1.f / 4096.f);
}

// ---------------------------------------------------------------------------
// Kernel 2: NCHW f32 -> padded NHWC bf16:  xt[b][h+1][w+1][c]
//   grid = B*64 (b,h), block 256.  Also zero-fills the halo.
// ---------------------------------------------------------------------------
__global__ void transform_kernel(const float* __restrict__ x,
                                 unsigned short* __restrict__ xt) {
    int blk = blockIdx.x;
    int b = blk >> 6, h = blk & 63;
    int t = threadIdx.x;
    int w  = t >> 2;          // 0..63
    int cg = (t & 3) * 8;     // channel group base

    const float* xp = x + ((size_t)(b * CIN + cg) * 64 + h) * 64 + w;
    short8 v;
    #pragma unroll
    for (int j = 0; j < 8; j++)
        v[j] = (short)f2bf(xp[(size_t)j * 4096]);

    *reinterpret_cast<short8*>(
        xt + (((size_t)b * 66 + (h + 1)) * 66 + (w + 1)) * 32 + cg) = v;

    // halo: top/bottom rows
    if (h == 0) {
        unsigned short* row0 = xt + (size_t)b * 66 * 66 * 32;
        for (int i = t; i < 66 * 32; i += 256) row0[i] = 0;
    }
    if (h == 63) {
        unsigned short* row65 = xt + ((size_t)b * 66 + 65) * 66 * 32;
        for (int i = t; i < 66 * 32; i += 256) row65[i] = 0;
    }
    // halo: left/right columns of this row
    if (t < 32)
        xt[(((size_t)b * 66 + (h + 1)) * 66 + 0) * 32 + t] = 0;
    else if (t < 64)
        xt[(((size_t)b * 66 + (h + 1)) * 66 + 65) * 32 + (t - 32)] = 0;
}

// ---------------------------------------------------------------------------
// Kernel 3: gating math, top-k, loss.  1 block x 64 threads, thread b = sample.
// ---------------------------------------------------------------------------
__global__ void gating_kernel(const float* __restrict__ gate_x,
                              const float* __restrict__ noise,
                              const float* __restrict__ w_gate,
                              const float* __restrict__ w_noise,
                              float* __restrict__ topg,
                              int* __restrict__ topidx,
                              float* __restrict__ loss_out) {
    __shared__ float s_wg[CIN * E];
    __shared__ float s_wn[CIN * E];
    __shared__ float s_g[B][E];
    __shared__ float s_p[B][E];
    __shared__ float s_imp[E];
    __shared__ float s_load[E];

    int t = threadIdx.x;
    for (int i = t; i < CIN * E; i += 64) {
        s_wg[i] = w_gate[i];
        s_wn[i] = w_noise[i];
    }
    __syncthreads();

    int b = t;
    float gx[CIN];
    #pragma unroll
    for (int c = 0; c < CIN; c++) gx[c] = gate_x[b * CIN + c];

    float clean[E], stdv[E], noisy[E];
    #pragma unroll
    for (int e = 0; e < E; e++) {
        float s1 = 0.f, s2 = 0.f;
        #pragma unroll
        for (int c = 0; c < CIN; c++) {
            s1 += gx[c] * s_wg[c * E + e];
            s2 += gx[c] * s_wn[c * E + e];
        }
        clean[e] = s1;
        float sp = fmaxf(s2, 0.f) + log1pf(expf(-fabsf(s2)));
        stdv[e]  = sp + 0.01f;
        noisy[e] = s1 + noise[b * E + e] * stdv[e];
    }

    float m = noisy[0];
    #pragma unroll
    for (int e = 1; e < E; e++) m = fmaxf(m, noisy[e]);
    float den = 0.f;
    float lg[E];
    #pragma unroll
    for (int e = 0; e < E; e++) { lg[e] = expf(noisy[e] - m); den += lg[e]; }
    float inv = 1.f / den;
    #pragma unroll
    for (int e = 0; e < E; e++) lg[e] *= inv;

    float tv[TOPK + 1];
    int   ti[TOPK + 1];
    bool  used[E];
    #pragma unroll
    for (int e = 0; e < E; e++) used[e] = false;
    for (int r = 0; r < TOPK + 1; r++) {
        float best = -1.f; int bi = 0;
        for (int e = 0; e < E; e++)
            if (!used[e] && lg[e] > best) { best = lg[e]; bi = e; }
        tv[r] = best; ti[r] = bi; used[bi] = true;
    }
    float s4 = tv[0] + tv[1] + tv[2] + tv[3] + 1e-6f;
    float grow[E];
    #pragma unroll
    for (int e = 0; e < E; e++) grow[e] = 0.f;
    for (int r = 0; r < TOPK; r++) {
        grow[ti[r]] = tv[r] / s4;
        topg[b * TOPK + r]   = tv[r] / s4;
        topidx[b * TOPK + r] = ti[r];
    }

    float thr_in  = tv[TOPK];
    float thr_out = tv[TOPK - 1];
    const float INV_SQRT2 = 0.70710678118654752f;
    #pragma unroll
    for (int e = 0; e < E; e++) {
        float thr = (noisy[e] > thr_in) ? thr_in : thr_out;
        float z = (clean[e] - thr) / stdv[e];
        s_p[b][e] = 0.5f * (1.f + erff(z * INV_SQRT2));
        s_g[b][e] = grow[e];
    }
    __syncthreads();

    if (t < E) {
        float si = 0.f, sl = 0.f;
        for (int bb = 0; bb < B; bb++) { si += s_g[bb][t]; sl += s_p[bb][t]; }
        s_imp[t] = si; s_load[t] = sl;
    }
    __syncthreads();

    if (t == 0) {
        float loss = 0.f;
        for (int pass = 0; pass < 2; pass++) {
            const float* v = pass == 0 ? s_imp : s_load;
            float mean = 0.f;
            for (int e = 0; e < E; e++) mean += v[e];
            mean *= (1.f / E);
            float var = 0.f;
            for (int e = 0; e < E; e++) { float d = v[e] - mean; var += d * d; }
            var *= (1.f / (E - 1));
            loss += var / (mean * mean + 1e-10f);
        }
        loss_out[0] = loss * 0.01f;
    }
}

// ---------------------------------------------------------------------------
// Kernel 4: combined per-sample weights -> bf16  cwb[b][tap][cout][cin]
//           and f32 cbias[b][cout].  Only the 4 active experts are read.
// ---------------------------------------------------------------------------
__global__ void combine_kernel(const float* __restrict__ topg,
                               const int* __restrict__ topidx,
                               const float* __restrict__ expert_w,
                               const float* __restrict__ expert_b,
                               unsigned short* __restrict__ cwb,
                               float* __restrict__ cbias) {
    int b = blockIdx.x;
    int t = threadIdx.x;
    __shared__ float g[TOPK];
    __shared__ int   gi[TOPK];
    if (t < TOPK) { g[t] = topg[b * TOPK + t]; gi[t] = topidx[b * TOPK + t]; }
    __syncthreads();
    float g0 = g[0], g1 = g[1], g2 = g[2], g3 = g[3];
    int   i0 = gi[0], i1 = gi[1], i2 = gi[2], i3 = gi[3];

    for (int o = t; o < 9 * COUT * CIN; o += 256) {
        int cin  = o & 31;
        int cout = (o >> 5) & 31;
        int tap  = o >> 10;
        int base = (cout * CIN + cin) * 9 + tap;
        float s = g0 * expert_w[i0 * 9216 + base] + g1 * expert_w[i1 * 9216 + base]
                + g2 * expert_w[i2 * 9216 + base] + g3 * expert_w[i3 * 9216 + base];
        cwb[(size_t)b * 9216 + o] = f2bf(s);
    }
    if (t < COUT) {
        cbias[b * COUT + t] = g0 * expert_b[i0 * COUT + t] + g1 * expert_b[i1 * COUT + t]
                            + g2 * expert_b[i2 * COUT + t] + g3 * expert_b[i3 * COUT + t];
    }
}

// ---------------------------------------------------------------------------
// Kernel 5: MFMA conv.  9 shifted GEMMs, K=32=cin in one mfma_f32_16x16x32_bf16.
//   grid = B*16 (4-row bands), block 256 = 4 waves, wave = one output row.
//   A-frags (weights) in 72 VGPRs; B-frags direct global loads from padded
//   NHWC xt (no LDS, no bounds checks).  D layout: col=lane&15 (px),
//   row=(lane>>4)*4+reg (cout).
// ---------------------------------------------------------------------------
__global__ void __launch_bounds__(256, 4)
conv_mfma(const unsigned short* __restrict__ xt,
          const unsigned short* __restrict__ cwb,
          const float* __restrict__ cbias,
          float* __restrict__ y) {
    int blk = blockIdx.x;
    int b  = blk >> 4;
    int hb = blk & 15;
    int t  = threadIdx.x;
    int wave = t >> 6, l = t & 63;
    int h  = hb * 4 + wave;            // output row
    int ln = l & 15;                   // n index (px) / m index (cout) for A
    int lk = l >> 4;                   // k group

    // A-fragments: cwb[b][tap][cout][cin]; lane: cout = ch*16+ln, cin = lk*8..+7
    const unsigned short* wbase = cwb + (size_t)b * 9216;
    short8 afrag[2][9];
    #pragma unroll
    for (int tap = 0; tap < 9; tap++) {
        #pragma unroll
        for (int ch = 0; ch < 2; ch++) {
            afrag[ch][tap] = *reinterpret_cast<const short8*>(
                wbase + tap * 1024 + (ch * 16 + ln) * 32 + lk * 8);
        }
    }

    float bias0[4], bias1[4];
    #pragma unroll
    for (int r = 0; r < 4; r++) {
        bias0[r] = cbias[b * COUT + lk * 4 + r];
        bias1[r] = cbias[b * COUT + 16 + lk * 4 + r];
    }

    const unsigned short* xb = xt + (size_t)b * 66 * 66 * 32;

    for (int tile = 0; tile < 4; tile++) {
        int w0 = tile * 16;
        f32x4 acc0 = {0.f, 0.f, 0.f, 0.f};
        f32x4 acc1 = {0.f, 0.f, 0.f, 0.f};
        #pragma unroll
        for (int kh = 0; kh < 3; kh++) {
            const unsigned short* xrow = xb + ((size_t)(h + kh) * 66 + w0 + ln) * 32 + lk * 8;
            #pragma unroll
            for (int kw = 0; kw < 3; kw++) {
                short8 bfrag = *reinterpret_cast<const short8*>(xrow + kw * 32);
                acc0 = __builtin_amdgcn_mfma_f32_16x16x32_bf16(afrag[0][kh * 3 + kw], bfrag, acc0, 0, 0, 0);
                acc1 = __builtin_amdgcn_mfma_f32_16x16x32_bf16(afrag[1][kh * 3 + kw], bfrag, acc1, 0, 0, 0);
            }
        }
        // store: w = w0+ln, cout = ch*16 + lk*4 + r
        #pragma unroll
        for (int r = 0; r < 4; r++) {
            y[((size_t)(b * COUT + lk * 4 + r) * 64 + h) * 64 + w0 + ln]      = acc0[r] + bias0[r];
            y[((size_t)(b * COUT + 16 + lk * 4 + r) * 64 + h) * 64 + w0 + ln] = acc1[r] + bias1[r];
        }
    }
}

// ---------------------------------------------------------------------------
extern "C" void kernel_launch(void* const* d_in, const int* in_sizes, int n_in,
                              void* d_out, int out_size, void* d_ws, size_t ws_size,
                              hipStream_t stream) {
    const float* x        = (const float*)d_in[0];
    const float* noise    = (const float*)d_in[1];
    const float* w_gate   = (const float*)d_in[2];
    const float* w_noise  = (const float*)d_in[3];
    const float* expert_w = (const float*)d_in[4];
    const float* expert_b = (const float*)d_in[5];

    float* y    = (float*)d_out;                        // 64*32*64*64
    float* loss = y + (size_t)B * COUT * HH * WW;

    // workspace layout (bytes)
    char* ws = (char*)d_ws;
    unsigned short* xt     = (unsigned short*)(ws);                 // 17,842,176 B
    unsigned short* cwb    = (unsigned short*)(ws + 17842176);      //  1,179,648 B
    float*          gate_x = (float*)(ws + 19021824);               //      8,192 B
    float*          topg   = (float*)(ws + 19030016);               //      1,024 B
    int*            topidx = (int*)  (ws + 19031040);               //      1,024 B
    float*          cbias  = (float*)(ws + 19032064);               //      8,192 B

    gatex_kernel<<<B * CIN, 256, 0, stream>>>(x, gate_x);
    transform_kernel<<<B * 64, 256, 0, stream>>>(x, xt);
    gating_kernel<<<1, 64, 0, stream>>>(gate_x, noise, w_gate, w_noise, topg, topidx, loss);
    combine_kernel<<<B, 256, 0, stream>>>(topg, topidx, expert_w, expert_b, cwb, cbias);
    conv_mfma<<<B * 16, 256, 0, stream>>>(xt, cwb, cbias, y);
}

// Round 3
// 55.946 us; speedup vs baseline: 2.8126x; 1.2717x over previous
//
#include <hip/hip_runtime.h>
#include <math.h>

// Problem constants
#define B 64
#define CIN 32
#define COUT 32
#define HH 64
#define WW 64
#define E 16
#define TOPK 4

typedef __attribute__((ext_vector_type(8))) short short8;
typedef __attribute__((ext_vector_type(4))) float f32x4;

// round-to-nearest-even f32 -> bf16 bits
__device__ __forceinline__ unsigned short f2bf(float f) {
    unsigned int u = __float_as_uint(f);
    u += 0x7fffu + ((u >> 16) & 1u);
    return (unsigned short)(u >> 16);
}

// ---------------------------------------------------------------------------
// Kernel 1: NCHW f32 -> padded NHWC bf16 xt[b][h+1][w+1][c], fused row-sum
//   for the gating mean.  grid = B*64 (b,h), block 256 = 4 waves.
//   Wave = 8-channel group (cg), lane = w.  Writes rowsum[b][h][c] (32 f).
// ---------------------------------------------------------------------------
__global__ void transform_gatex(const float* __restrict__ x,
                                unsigned short* __restrict__ xt,
                                float* __restrict__ rowsum) {
    int blk = blockIdx.x;
    int b = blk >> 6, h = blk & 63;
    int t = threadIdx.x;
    int w  = t & 63;
    int cg = (t >> 6) * 8;    // channel group base (wave-uniform)

    const float* xp = x + ((size_t)(b * CIN + cg) * 64 + h) * 64 + w;
    float v[8];
    short8 o;
    #pragma unroll
    for (int j = 0; j < 8; j++) {
        v[j] = xp[(size_t)j * 4096];
        o[j] = (short)f2bf(v[j]);
    }
    *reinterpret_cast<short8*>(
        xt + (((size_t)b * 66 + (h + 1)) * 66 + (w + 1)) * 32 + cg) = o;

    // full-wave reduce of the 8 channel sums over the 64 w's
    #pragma unroll
    for (int off = 1; off < 64; off <<= 1)
        #pragma unroll
        for (int j = 0; j < 8; j++) v[j] += __shfl_xor(v[j], off, 64);

    __shared__ float s_rs[4][8];
    if ((t & 63) == 0) {
        #pragma unroll
        for (int j = 0; j < 8; j++) s_rs[t >> 6][j] = v[j];
    }
    __syncthreads();
    if (t < 32) rowsum[((size_t)b * 64 + h) * 32 + t] = s_rs[t >> 3][t & 7];

    // halo zero-fill
    if (h == 0) {
        unsigned short* row0 = xt + (size_t)b * 66 * 66 * 32;
        for (int i = t; i < 66 * 32; i += 256) row0[i] = 0;
    }
    if (h == 63) {
        unsigned short* row65 = xt + ((size_t)b * 66 + 65) * 66 * 32;
        for (int i = t; i < 66 * 32; i += 256) row65[i] = 0;
    }
    if (t < 32)
        xt[(((size_t)b * 66 + (h + 1)) * 66 + 0) * 32 + t] = 0;
    else if (t < 64)
        xt[(((size_t)b * 66 + (h + 1)) * 66 + 65) * 32 + (t - 32)] = 0;
}

// ---------------------------------------------------------------------------
// Kernel 2: per-sample gating (recomputed per block from rowsum) + combined
//   weights.  grid = B, block 256.
//   Outputs: cwb[b][tap][cout][cin] bf16, cbias[b][cout] f32,
//            probw[b][e], gimpw[b][e] (for the loss kernel).
// ---------------------------------------------------------------------------
__global__ void combine_gating(const float* __restrict__ rowsum,
                               const float* __restrict__ noise,
                               const float* __restrict__ w_gate,
                               const float* __restrict__ w_noise,
                               const float* __restrict__ expert_w,
                               const float* __restrict__ expert_b,
                               unsigned short* __restrict__ cwb,
                               float* __restrict__ cbias,
                               float* __restrict__ probw,
                               float* __restrict__ gimpw) {
    int b = blockIdx.x;
    int t = threadIdx.x;

    __shared__ float s_part[8][32];
    __shared__ float gx[32];
    __shared__ float s_clean[E], s_std[E], s_noisy[E];
    __shared__ float s_tv[TOPK + 1];
    __shared__ float s_grow[E];
    __shared__ float s_g[TOPK];
    __shared__ int   s_gi[TOPK];

    // gate_x[b][c] = mean: reduce 64 rowsums per channel
    {
        int c = t & 31, hg = t >> 5;
        const float* rp = rowsum + ((size_t)b * 64 + hg * 8) * 32 + c;
        float s = 0.f;
        #pragma unroll
        for (int j = 0; j < 8; j++) s += rp[j * 32];
        s_part[hg][c] = s;
    }
    __syncthreads();
    if (t < 32) {
        float s = 0.f;
        #pragma unroll
        for (int hg = 0; hg < 8; hg++) s += s_part[hg][t];
        gx[t] = s * (1.f / 4096.f);
    }
    __syncthreads();

    if (t < E) {
        int e = t;
        float s1 = 0.f, s2 = 0.f;
        #pragma unroll
        for (int c = 0; c < CIN; c++) {
            float g = gx[c];
            s1 += g * w_gate[c * E + e];
            s2 += g * w_noise[c * E + e];
        }
        float sp = fmaxf(s2, 0.f) + log1pf(expf(-fabsf(s2)));
        s_clean[e] = s1;
        s_std[e]   = sp + 0.01f;
        s_noisy[e] = s1 + noise[b * E + e] * (sp + 0.01f);
    }
    __syncthreads();

    if (t == 0) {
        float lg[E];
        float m = s_noisy[0];
        #pragma unroll
        for (int e = 1; e < E; e++) m = fmaxf(m, s_noisy[e]);
        float den = 0.f;
        #pragma unroll
        for (int e = 0; e < E; e++) { lg[e] = expf(s_noisy[e] - m); den += lg[e]; }
        float inv = 1.f / den;
        #pragma unroll
        for (int e = 0; e < E; e++) lg[e] *= inv;

        bool used[E];
        #pragma unroll
        for (int e = 0; e < E; e++) { used[e] = false; s_grow[e] = 0.f; }
        float tv[TOPK + 1]; int ti[TOPK + 1];
        for (int r = 0; r < TOPK + 1; r++) {
            float best = -1.f; int bi = 0;
            for (int e = 0; e < E; e++)
                if (!used[e] && lg[e] > best) { best = lg[e]; bi = e; }
            tv[r] = best; ti[r] = bi; used[bi] = true;
            s_tv[r] = best;
        }
        float s4 = tv[0] + tv[1] + tv[2] + tv[3] + 1e-6f;
        for (int r = 0; r < TOPK; r++) {
            float gr = tv[r] / s4;
            s_grow[ti[r]] = gr;
            s_g[r] = gr; s_gi[r] = ti[r];
        }
    }
    __syncthreads();

    if (t < E) {
        const float INV_SQRT2 = 0.70710678118654752f;
        float thr_in = s_tv[TOPK], thr_out = s_tv[TOPK - 1];
        float thr = (s_noisy[t] > thr_in) ? thr_in : thr_out;
        float z = (s_clean[t] - thr) / s_std[t];
        probw[b * E + t] = 0.5f * (1.f + erff(z * INV_SQRT2));
        gimpw[b * E + t] = s_grow[t];
    }

    float g0 = s_g[0], g1 = s_g[1], g2 = s_g[2], g3 = s_g[3];
    int   i0 = s_gi[0], i1 = s_gi[1], i2 = s_gi[2], i3 = s_gi[3];

    // combined weights: o iterates expert_w's native layout (coalesced reads),
    // store scattered into cwb[b][tap][cout][cin]
    for (int o = t; o < 9 * COUT * CIN; o += 256) {
        int tap = o % 9;
        int q   = o / 9;           // cout*32 + cin
        int cin = q & 31, cout = q >> 5;
        float s = g0 * expert_w[i0 * 9216 + o] + g1 * expert_w[i1 * 9216 + o]
                + g2 * expert_w[i2 * 9216 + o] + g3 * expert_w[i3 * 9216 + o];
        cwb[(size_t)b * 9216 + tap * 1024 + cout * 32 + cin] = f2bf(s);
    }
    if (t < COUT) {
        cbias[b * COUT + t] = g0 * expert_b[i0 * COUT + t] + g1 * expert_b[i1 * COUT + t]
                            + g2 * expert_b[i2 * COUT + t] + g3 * expert_b[i3 * COUT + t];
    }
}

// ---------------------------------------------------------------------------
// Kernel 3: MFMA conv.  9 shifted GEMMs, K=32=cin in one mfma_f32_16x16x32_bf16.
//   grid = B*16 (4-row bands), block 256 = 4 waves, wave = one output row.
// ---------------------------------------------------------------------------
__global__ void __launch_bounds__(256, 4)
conv_mfma(const unsigned short* __restrict__ xt,
          const unsigned short* __restrict__ cwb,
          const float* __restrict__ cbias,
          float* __restrict__ y) {
    int blk = blockIdx.x;
    int b  = blk >> 4;
    int hb = blk & 15;
    int t  = threadIdx.x;
    int wave = t >> 6, l = t & 63;
    int h  = hb * 4 + wave;            // output row
    int ln = l & 15;                   // n (px) / m (cout) index
    int lk = l >> 4;                   // k group

    const unsigned short* wbase = cwb + (size_t)b * 9216;
    short8 afrag[2][9];
    #pragma unroll
    for (int tap = 0; tap < 9; tap++) {
        #pragma unroll
        for (int ch = 0; ch < 2; ch++) {
            afrag[ch][tap] = *reinterpret_cast<const short8*>(
                wbase + tap * 1024 + (ch * 16 + ln) * 32 + lk * 8);
        }
    }

    float bias0[4], bias1[4];
    #pragma unroll
    for (int r = 0; r < 4; r++) {
        bias0[r] = cbias[b * COUT + lk * 4 + r];
        bias1[r] = cbias[b * COUT + 16 + lk * 4 + r];
    }

    const unsigned short* xb = xt + (size_t)b * 66 * 66 * 32;

    for (int tile = 0; tile < 4; tile++) {
        int w0 = tile * 16;
        f32x4 acc0 = {0.f, 0.f, 0.f, 0.f};
        f32x4 acc1 = {0.f, 0.f, 0.f, 0.f};
        #pragma unroll
        for (int kh = 0; kh < 3; kh++) {
            const unsigned short* xrow = xb + ((size_t)(h + kh) * 66 + w0 + ln) * 32 + lk * 8;
            #pragma unroll
            for (int kw = 0; kw < 3; kw++) {
                short8 bfrag = *reinterpret_cast<const short8*>(xrow + kw * 32);
                acc0 = __builtin_amdgcn_mfma_f32_16x16x32_bf16(afrag[0][kh * 3 + kw], bfrag, acc0, 0, 0, 0);
                acc1 = __builtin_amdgcn_mfma_f32_16x16x32_bf16(afrag[1][kh * 3 + kw], bfrag, acc1, 0, 0, 0);
            }
        }
        #pragma unroll
        for (int r = 0; r < 4; r++) {
            y[((size_t)(b * COUT + lk * 4 + r) * 64 + h) * 64 + w0 + ln]      = acc0[r] + bias0[r];
            y[((size_t)(b * COUT + 16 + lk * 4 + r) * 64 + h) * 64 + w0 + ln] = acc1[r] + bias1[r];
        }
    }
}

// ---------------------------------------------------------------------------
// Kernel 4: loss from per-sample prob / gate rows.  1 block, 64 threads.
// ---------------------------------------------------------------------------
__global__ void loss_kernel(const float* __restrict__ probw,
                            const float* __restrict__ gimpw,
                            float* __restrict__ loss_out) {
    __shared__ float s_imp[E], s_load[E];
    int t = threadIdx.x;
    if (t < E) {
        float si = 0.f, sl = 0.f;
        for (int b = 0; b < B; b++) {
            si += gimpw[b * E + t];
            sl += probw[b * E + t];
        }
        s_imp[t] = si; s_load[t] = sl;
    }
    __syncthreads();
    if (t == 0) {
        float loss = 0.f;
        for (int pass = 0; pass < 2; pass++) {
            const float* v = pass == 0 ? s_imp : s_load;
            float mean = 0.f;
            for (int e = 0; e < E; e++) mean += v[e];
            mean *= (1.f / E);
            float var = 0.f;
            for (int e = 0; e < E; e++) { float d = v[e] - mean; var += d * d; }
            var *= (1.f / (E - 1));
            loss += var / (mean * mean + 1e-10f);
        }
        loss_out[0] = loss * 0.01f;
    }
}

// ---------------------------------------------------------------------------
extern "C" void kernel_launch(void* const* d_in, const int* in_sizes, int n_in,
                              void* d_out, int out_size, void* d_ws, size_t ws_size,
                              hipStream_t stream) {
    const float* x        = (const float*)d_in[0];
    const float* noise    = (const float*)d_in[1];
    const float* w_gate   = (const float*)d_in[2];
    const float* w_noise  = (const float*)d_in[3];
    const float* expert_w = (const float*)d_in[4];
    const float* expert_b = (const float*)d_in[5];

    float* y    = (float*)d_out;
    float* loss = y + (size_t)B * COUT * HH * WW;

    char* ws = (char*)d_ws;
    unsigned short* xt     = (unsigned short*)(ws);             // 17,842,176 B
    float*          rowsum = (float*)(ws + 17842176);           //    524,288 B
    unsigned short* cwb    = (unsigned short*)(ws + 18366464);  //  1,179,648 B
    float*          cbias  = (float*)(ws + 19546112);           //      8,192 B
    float*          probw  = (float*)(ws + 19554304);           //      4,096 B
    float*          gimpw  = (float*)(ws + 19558400);           //      4,096 B

    transform_gatex<<<B * 64, 256, 0, stream>>>(x, xt, rowsum);
    combine_gating<<<B, 256, 0, stream>>>(rowsum, noise, w_gate, w_noise,
                                          expert_w, expert_b, cwb, cbias, probw, gimpw);
    conv_mfma<<<B * 16, 256, 0, stream>>>(xt, cwb, cbias, y);
    loss_kernel<<<1, 64, 0, stream>>>(probw, gimpw, loss);
}